// Round 1
// baseline (429.526 us; speedup 1.0000x reference)
//
#include <hip/hip_runtime.h>

typedef unsigned short u16;
typedef u16 u16x8 __attribute__((ext_vector_type(8)));
typedef __bf16 bf16x8 __attribute__((ext_vector_type(8)));
typedef float f32x4 __attribute__((ext_vector_type(4)));

#define T_TOK 1024
#define H_DIM 2048
#define E_NUM 16
#define I_DIM 704
#define IS_DIM 1408
#define EI_DIM (E_NUM * I_DIM) /* 11264 */

#define MFMA(a, b, c) __builtin_amdgcn_mfma_f32_16x16x32_bf16(a, b, c, 0, 0, 0)

__device__ __forceinline__ u16 f2bf(float f) {
  union { float f; unsigned u; } v; v.f = f;
  unsigned r = v.u + 0x7fffu + ((v.u >> 16) & 1u);
  return (u16)(r >> 16);
}

// Swizzled LDS address within 128-byte rows: XOR bits[6:4] with (row&7)
__device__ __forceinline__ char* lds_sw(char* base, int row, int kByte) {
  return base + row * 128 + (kByte ^ ((row & 7) << 4));
}

// Stage a tile of (CNT*32) rows x 64 bf16 cols from row-major src (element
// stride `stride`) into swizzled LDS rows of 128B. 256 threads.
template <int CNT>
__device__ __forceinline__ void stage_tile(const u16* __restrict__ src, size_t stride,
                                           u16* lds, int tid) {
#pragma unroll
  for (int i = 0; i < CNT; ++i) {
    int c = i * 256 + tid;
    int m = c >> 3, k8 = c & 7;
    u16x8 v = *(const u16x8*)(src + (size_t)m * stride + k8 * 8);
    *(u16x8*)lds_sw((char*)lds, m, k8 * 16) = v;
  }
}

// ---------------- x fp32 -> bf16 ----------------
__global__ __launch_bounds__(256) void conv_x_k(const float* __restrict__ in,
                                                u16* __restrict__ outp) {
  const int i = (blockIdx.x * 256 + threadIdx.x) * 8;
  f32x4 a = *(const f32x4*)(in + i);
  f32x4 b = *(const f32x4*)(in + i + 4);
  u16x8 o;
  o[0] = f2bf(a[0]); o[1] = f2bf(a[1]); o[2] = f2bf(a[2]); o[3] = f2bf(a[3]);
  o[4] = f2bf(b[0]); o[5] = f2bf(b[1]); o[6] = f2bf(b[2]); o[7] = f2bf(b[3]);
  *(u16x8*)(outp + i) = o;
}

// ---------------- transpose + convert: [R][C] f32 -> [C][R] bf16 ----------------
__global__ __launch_bounds__(256) void transp_k(const float* __restrict__ in,
                                                u16* __restrict__ outp, int R, int C) {
  __shared__ float tile[32][33];
  const size_t base = (size_t)blockIdx.z * (size_t)R * C;
  const int c0 = blockIdx.x * 32, r0 = blockIdx.y * 32;
  const int tx = threadIdx.x, ty = threadIdx.y; // (32,8)
#pragma unroll
  for (int i = 0; i < 32; i += 8)
    tile[ty + i][tx] = in[base + (size_t)(r0 + ty + i) * C + c0 + tx];
  __syncthreads();
#pragma unroll
  for (int i = 0; i < 32; i += 8)
    outp[base + (size_t)(c0 + ty + i) * R + r0 + tx] = f2bf(tile[tx][ty + i]);
}

// ---------------- router: logits -> softmax -> grouped top-k -> combine*2.5 ----------------
__global__ __launch_bounds__(256) void router_k(const float* __restrict__ x,
                                                const float* __restrict__ wg,
                                                float* __restrict__ comb) {
  const int t = blockIdx.x;
  const int tid = threadIdx.x;
  float acc[E_NUM];
#pragma unroll
  for (int e = 0; e < E_NUM; ++e) acc[e] = 0.f;
  const float* xr = x + (size_t)t * H_DIM;
  for (int h = tid; h < H_DIM; h += 256) {
    const float xv = xr[h];
    const f32x4* wr = (const f32x4*)(wg + (size_t)h * E_NUM);
#pragma unroll
    for (int q = 0; q < 4; ++q) {
      f32x4 w4 = wr[q];
      acc[q * 4 + 0] += xv * w4[0];
      acc[q * 4 + 1] += xv * w4[1];
      acc[q * 4 + 2] += xv * w4[2];
      acc[q * 4 + 3] += xv * w4[3];
    }
  }
#pragma unroll
  for (int e = 0; e < E_NUM; ++e)
    for (int off = 32; off > 0; off >>= 1) acc[e] += __shfl_down(acc[e], off);
  __shared__ float part[4][E_NUM];
  if ((tid & 63) == 0) {
#pragma unroll
    for (int e = 0; e < E_NUM; ++e) part[tid >> 6][e] = acc[e];
  }
  __syncthreads();
  if (tid == 0) {
    float p[E_NUM];
    float mx = -1e30f;
    for (int e = 0; e < E_NUM; ++e) {
      p[e] = part[0][e] + part[1][e] + part[2][e] + part[3][e];
      mx = fmaxf(mx, p[e]);
    }
    float s = 0.f;
    for (int e = 0; e < E_NUM; ++e) { p[e] = __expf(p[e] - mx); s += p[e]; }
    const float invs = 1.f / s;
    for (int e = 0; e < E_NUM; ++e) p[e] *= invs;
    // group scores (groups of 4), pick top-2 groups (ties -> lower index)
    float gs[4];
    for (int g = 0; g < 4; ++g)
      gs[g] = fmaxf(fmaxf(p[4 * g], p[4 * g + 1]), fmaxf(p[4 * g + 2], p[4 * g + 3]));
    int g1 = 0;
    for (int g = 1; g < 4; ++g) if (gs[g] > gs[g1]) g1 = g;
    int g2 = -1;
    for (int g = 0; g < 4; ++g) {
      if (g == g1) continue;
      if (g2 < 0 || gs[g] > gs[g2]) g2 = g;
    }
    float m2[E_NUM], cw[E_NUM];
    for (int e = 0; e < E_NUM; ++e) {
      int g = e >> 2;
      m2[e] = (g == g1 || g == g2) ? p[e] : 0.f;
      cw[e] = 0.f;
    }
    float sum6 = 0.f;
    for (int k = 0; k < 6; ++k) { // top-6, ties -> lower index
      int bi = 0; float bv = -1.f;
      for (int e = 0; e < E_NUM; ++e)
        if (m2[e] > bv) { bv = m2[e]; bi = e; }
      cw[bi] = bv; sum6 += bv; m2[bi] = -2.f;
    }
    const float scale = 2.5f / sum6; // fold ROUTED_SCALING into combine
    for (int e = 0; e < E_NUM; ++e) comb[t * E_NUM + e] = cw[e] * scale;
  }
}

// ---------------- fused gate/up GEMM + silu*u*combine -> bf16 act ----------------
// A: [1024][2048] bf16. Bt: transposed weights, per-expert [ncols][2048].
// Block: BM=128 x BN=64, computes g-tile (rows n0..) and u-tile (rows gu_off+n0..).
__global__ __launch_bounds__(256, 2) void gu_act_k(
    const u16* __restrict__ A, const u16* __restrict__ Bt,
    const float* __restrict__ comb, u16* __restrict__ outp,
    int gu_off, long long bt_e_stride, int out_stride, int out_e_stride) {
  __shared__ __align__(16) u16 As[128 * 64];
  __shared__ __align__(16) u16 Bg[64 * 64];
  __shared__ __align__(16) u16 Bu[64 * 64];

  const int n0 = blockIdx.x * 64;
  const int m0 = blockIdx.y * 128;
  const int e = blockIdx.z;
  const u16* Bte = Bt + (size_t)e * bt_e_stride;
  const int tid = threadIdx.x;
  const int lane = tid & 63;
  const int wr = tid >> 7;
  const int wc = (tid >> 6) & 1;
  const int fr = lane & 15;
  const int fg = lane >> 4;

  const f32x4 zero = {0.f, 0.f, 0.f, 0.f};
  f32x4 accg[4][2], accu[4][2];
#pragma unroll
  for (int i = 0; i < 4; ++i)
#pragma unroll
    for (int j = 0; j < 2; ++j) { accg[i][j] = zero; accu[i][j] = zero; }

  for (int kt = 0; kt < H_DIM / 64; ++kt) {
    const int k0 = kt * 64;
    stage_tile<4>(A + (size_t)m0 * H_DIM + k0, H_DIM, As, tid);
    stage_tile<2>(Bte + (size_t)n0 * H_DIM + k0, H_DIM, Bg, tid);
    stage_tile<2>(Bte + (size_t)(gu_off + n0) * H_DIM + k0, H_DIM, Bu, tid);
    __syncthreads();
#pragma unroll
    for (int kk = 0; kk < 2; ++kk) {
      const int kb = kk * 64 + fg * 16;
      bf16x8 af[4], bg[2], bu[2];
#pragma unroll
      for (int mi = 0; mi < 4; ++mi)
        af[mi] = *(const bf16x8*)lds_sw((char*)As, wr * 64 + mi * 16 + fr, kb);
#pragma unroll
      for (int ni = 0; ni < 2; ++ni) {
        bg[ni] = *(const bf16x8*)lds_sw((char*)Bg, wc * 32 + ni * 16 + fr, kb);
        bu[ni] = *(const bf16x8*)lds_sw((char*)Bu, wc * 32 + ni * 16 + fr, kb);
      }
#pragma unroll
      for (int mi = 0; mi < 4; ++mi)
#pragma unroll
        for (int ni = 0; ni < 2; ++ni) {
          accg[mi][ni] = MFMA(af[mi], bg[ni], accg[mi][ni]);
          accu[mi][ni] = MFMA(af[mi], bu[ni], accu[mi][ni]);
        }
    }
    __syncthreads();
  }

  const int colb = e * out_e_stride + n0 + wc * 32;
#pragma unroll
  for (int mi = 0; mi < 4; ++mi) {
#pragma unroll
    for (int r = 0; r < 4; ++r) {
      const int t = m0 + wr * 64 + mi * 16 + fg * 4 + r;
      const float wgt = comb ? comb[t * E_NUM + e] : 1.0f;
#pragma unroll
      for (int ni = 0; ni < 2; ++ni) {
        float g = accg[mi][ni][r];
        float u = accu[mi][ni][r];
        float sg = g / (1.f + __expf(-g));
        outp[(size_t)t * out_stride + colb + ni * 16 + fr] = f2bf(sg * u * wgt);
      }
    }
  }
}

// ---------------- down projection: out = actS @ WsdT^T + ACT @ WdT^T ----------------
// BM=64 x BN=64, two K phases accumulate into the same f32 tile.
__global__ __launch_bounds__(256, 2) void down_k(
    const u16* __restrict__ A1, const u16* __restrict__ B1t, // actS [1024][1408], WsdT [2048][1408]
    const u16* __restrict__ A2, const u16* __restrict__ B2t, // ACT [1024][11264], WdT [16][2048][704]
    float* __restrict__ outp) {
  __shared__ __align__(16) u16 As[64 * 64];
  __shared__ __align__(16) u16 Bs[64 * 64];
  const int n0 = blockIdx.x * 64; // H
  const int m0 = blockIdx.y * 64; // T
  const int tid = threadIdx.x;
  const int lane = tid & 63;
  const int wr = tid >> 7, wc = (tid >> 6) & 1;
  const int fr = lane & 15, fg = lane >> 4;

  const f32x4 zero = {0.f, 0.f, 0.f, 0.f};
  f32x4 acc[2][2];
#pragma unroll
  for (int i = 0; i < 2; ++i)
#pragma unroll
    for (int j = 0; j < 2; ++j) acc[i][j] = zero;

  // phase 1: shared expert down, K = 1408
  for (int kt = 0; kt < IS_DIM / 64; ++kt) {
    const int k0 = kt * 64;
    stage_tile<2>(A1 + (size_t)m0 * IS_DIM + k0, IS_DIM, As, tid);
    stage_tile<2>(B1t + (size_t)n0 * IS_DIM + k0, IS_DIM, Bs, tid);
    __syncthreads();
#pragma unroll
    for (int kk = 0; kk < 2; ++kk) {
      const int kb = kk * 64 + fg * 16;
      bf16x8 af[2], bfr[2];
#pragma unroll
      for (int mi = 0; mi < 2; ++mi)
        af[mi] = *(const bf16x8*)lds_sw((char*)As, wr * 32 + mi * 16 + fr, kb);
#pragma unroll
      for (int ni = 0; ni < 2; ++ni)
        bfr[ni] = *(const bf16x8*)lds_sw((char*)Bs, wc * 32 + ni * 16 + fr, kb);
#pragma unroll
      for (int mi = 0; mi < 2; ++mi)
#pragma unroll
        for (int ni = 0; ni < 2; ++ni) acc[mi][ni] = MFMA(af[mi], bfr[ni], acc[mi][ni]);
    }
    __syncthreads();
  }
  // phase 2: routed down, K = 11264 (11 k-tiles per expert, exact)
  for (int kt = 0; kt < EI_DIM / 64; ++kt) {
    const int e = kt / 11;
    const int i0 = (kt - e * 11) * 64;
    stage_tile<2>(A2 + (size_t)m0 * EI_DIM + kt * 64, EI_DIM, As, tid);
    stage_tile<2>(B2t + ((size_t)e * H_DIM + n0) * I_DIM + i0, I_DIM, Bs, tid);
    __syncthreads();
#pragma unroll
    for (int kk = 0; kk < 2; ++kk) {
      const int kb = kk * 64 + fg * 16;
      bf16x8 af[2], bfr[2];
#pragma unroll
      for (int mi = 0; mi < 2; ++mi)
        af[mi] = *(const bf16x8*)lds_sw((char*)As, wr * 32 + mi * 16 + fr, kb);
#pragma unroll
      for (int ni = 0; ni < 2; ++ni)
        bfr[ni] = *(const bf16x8*)lds_sw((char*)Bs, wc * 32 + ni * 16 + fr, kb);
#pragma unroll
      for (int mi = 0; mi < 2; ++mi)
#pragma unroll
        for (int ni = 0; ni < 2; ++ni) acc[mi][ni] = MFMA(af[mi], bfr[ni], acc[mi][ni]);
    }
    __syncthreads();
  }

#pragma unroll
  for (int mi = 0; mi < 2; ++mi)
#pragma unroll
    for (int r = 0; r < 4; ++r)
#pragma unroll
      for (int ni = 0; ni < 2; ++ni)
        outp[(size_t)(m0 + wr * 32 + mi * 16 + fg * 4 + r) * H_DIM + n0 + wc * 32 +
             ni * 16 + fr] = acc[mi][ni][r];
}

extern "C" void kernel_launch(void* const* d_in, const int* in_sizes, int n_in,
                              void* d_out, int out_size, void* d_ws, size_t ws_size,
                              hipStream_t stream) {
  const float* x    = (const float*)d_in[0];
  const float* wg   = (const float*)d_in[1];
  const float* wgu  = (const float*)d_in[2];
  const float* wd   = (const float*)d_in[3];
  const float* wsgu = (const float*)d_in[4];
  const float* wsd  = (const float*)d_in[5];
  float* out = (float*)d_out;

  char* ws = (char*)d_ws;
  size_t off = 0;
  auto alloc = [&](size_t b) { size_t r = off; off += (b + 255) & ~(size_t)255; return r; };
  u16*   XB    = (u16*)  (ws + alloc((size_t)T_TOK * H_DIM * 2));        // x bf16
  float* COMB  = (float*)(ws + alloc((size_t)T_TOK * E_NUM * 4));        // combine*2.5
  u16*   WGUT  = (u16*)  (ws + alloc((size_t)E_NUM * 2 * I_DIM * H_DIM * 2)); // [e][1408][2048]
  u16*   WDT   = (u16*)  (ws + alloc((size_t)E_NUM * H_DIM * I_DIM * 2));     // [e][2048][704]
  u16*   WSGUT = (u16*)  (ws + alloc((size_t)2 * IS_DIM * H_DIM * 2));        // [2816][2048]
  u16*   WSDT  = (u16*)  (ws + alloc((size_t)H_DIM * IS_DIM * 2));            // [2048][1408]
  u16*   ACT   = (u16*)  (ws + alloc((size_t)T_TOK * EI_DIM * 2));            // [1024][11264]
  u16*   ACTS  = (u16*)  (ws + alloc((size_t)T_TOK * IS_DIM * 2));            // [1024][1408]
  if (ws_size < off) return; // ws too small: leave output zero (distinct failure signature)

  conv_x_k<<<(T_TOK * H_DIM) / (256 * 8), 256, 0, stream>>>(x, XB);
  router_k<<<T_TOK, 256, 0, stream>>>(x, wg, COMB);
  // weight transposes fp32 -> bf16 [N][K]
  transp_k<<<dim3(44, 64, 16), dim3(32, 8), 0, stream>>>(wgu, WGUT, H_DIM, 2 * I_DIM);
  transp_k<<<dim3(64, 22, 16), dim3(32, 8), 0, stream>>>(wd, WDT, I_DIM, H_DIM);
  transp_k<<<dim3(88, 64, 1), dim3(32, 8), 0, stream>>>(wsgu, WSGUT, H_DIM, 2 * IS_DIM);
  transp_k<<<dim3(64, 44, 1), dim3(32, 8), 0, stream>>>(wsd, WSDT, IS_DIM, H_DIM);
  // routed experts gate/up + act (dense all-experts; combine weights zero out unselected)
  gu_act_k<<<dim3(I_DIM / 64, T_TOK / 128, E_NUM), 256, 0, stream>>>(
      XB, WGUT, COMB, ACT, I_DIM, (long long)(2 * I_DIM) * H_DIM, EI_DIM, I_DIM);
  // shared expert gate/up + act
  gu_act_k<<<dim3(IS_DIM / 64, T_TOK / 128, 1), 256, 0, stream>>>(
      XB, WSGUT, nullptr, ACTS, IS_DIM, 0, IS_DIM, 0);
  // fused down projection (shared K=1408, routed K=11264) -> f32 out
  down_k<<<dim3(H_DIM / 64, T_TOK / 64), 256, 0, stream>>>(ACTS, WSDT, ACT, WDT, out);
}

// Round 2
// 327.096 us; speedup vs baseline: 1.3132x; 1.3132x over previous
//
#include <hip/hip_runtime.h>

typedef unsigned short u16;
typedef u16 u16x8 __attribute__((ext_vector_type(8)));
typedef __bf16 bf16x8 __attribute__((ext_vector_type(8)));
typedef float f32x4 __attribute__((ext_vector_type(4)));

#define T_TOK 1024
#define H_DIM 2048
#define E_NUM 16
#define I_DIM 704
#define IS_DIM 1408
#define EI_DIM (E_NUM * I_DIM) /* 11264 */

#define MFMA(a, b, c) __builtin_amdgcn_mfma_f32_16x16x32_bf16(a, b, c, 0, 0, 0)

__device__ __forceinline__ u16 f2bf(float f) {
  union { float f; unsigned u; } v; v.f = f;
  unsigned r = v.u + 0x7fffu + ((v.u >> 16) & 1u);
  return (u16)(r >> 16);
}

// Swizzled LDS address within 128-byte rows: XOR bits[6:4] with (row&7)
__device__ __forceinline__ char* lds_sw(char* base, int row, int kByte) {
  return base + row * 128 + (kByte ^ ((row & 7) << 4));
}

// Stage (CNT*32) rows x 64 bf16 cols from row-major src into swizzled LDS rows.
template <int CNT>
__device__ __forceinline__ void stage_tile(const u16* __restrict__ src, size_t stride,
                                           u16* lds, int tid) {
#pragma unroll
  for (int i = 0; i < CNT; ++i) {
    int c = i * 256 + tid;
    int m = c >> 3, k8 = c & 7;
    u16x8 v = *(const u16x8*)(src + (size_t)m * stride + k8 * 8);
    *(u16x8*)lds_sw((char*)lds, m, k8 * 16) = v;
  }
}

// Gather variant: row m comes from token list tokS (LDS).
template <int CNT>
__device__ __forceinline__ void stage_gather(const u16* __restrict__ src, size_t stride,
                                             const int* tokS, u16* lds, int tid) {
#pragma unroll
  for (int i = 0; i < CNT; ++i) {
    int c = i * 256 + tid;
    int m = c >> 3, k8 = c & 7;
    u16x8 v = *(const u16x8*)(src + (size_t)tokS[m] * stride + k8 * 8);
    *(u16x8*)lds_sw((char*)lds, m, k8 * 16) = v;
  }
}

// ---------------- x fp32 -> bf16 ----------------
__global__ __launch_bounds__(256) void conv_x_k(const float* __restrict__ in,
                                                u16* __restrict__ outp) {
  const int i = (blockIdx.x * 256 + threadIdx.x) * 8;
  f32x4 a = *(const f32x4*)(in + i);
  f32x4 b = *(const f32x4*)(in + i + 4);
  u16x8 o;
  o[0] = f2bf(a[0]); o[1] = f2bf(a[1]); o[2] = f2bf(a[2]); o[3] = f2bf(a[3]);
  o[4] = f2bf(b[0]); o[5] = f2bf(b[1]); o[6] = f2bf(b[2]); o[7] = f2bf(b[3]);
  *(u16x8*)(outp + i) = o;
}

// ---------------- transpose + convert: [R][C] f32 -> [C][R] bf16 ----------------
__global__ __launch_bounds__(256) void transp_k(const float* __restrict__ in,
                                                u16* __restrict__ outp, int R, int C) {
  __shared__ float tile[32][33];
  const size_t base = (size_t)blockIdx.z * (size_t)R * C;
  const int c0 = blockIdx.x * 32, r0 = blockIdx.y * 32;
  const int tx = threadIdx.x, ty = threadIdx.y; // (32,8)
#pragma unroll
  for (int i = 0; i < 32; i += 8)
    tile[ty + i][tx] = in[base + (size_t)(r0 + ty + i) * C + c0 + tx];
  __syncthreads();
#pragma unroll
  for (int i = 0; i < 32; i += 8)
    outp[base + (size_t)(c0 + ty + i) * R + r0 + tx] = f2bf(tile[tx][ty + i]);
}

// ---------------- router ----------------
__global__ __launch_bounds__(256) void router_k(const float* __restrict__ x,
                                                const float* __restrict__ wg,
                                                float* __restrict__ comb) {
  const int t = blockIdx.x;
  const int tid = threadIdx.x;
  float acc[E_NUM];
#pragma unroll
  for (int e = 0; e < E_NUM; ++e) acc[e] = 0.f;
  const float* xr = x + (size_t)t * H_DIM;
  for (int h = tid; h < H_DIM; h += 256) {
    const float xv = xr[h];
    const f32x4* wr = (const f32x4*)(wg + (size_t)h * E_NUM);
#pragma unroll
    for (int q = 0; q < 4; ++q) {
      f32x4 w4 = wr[q];
      acc[q * 4 + 0] += xv * w4[0];
      acc[q * 4 + 1] += xv * w4[1];
      acc[q * 4 + 2] += xv * w4[2];
      acc[q * 4 + 3] += xv * w4[3];
    }
  }
#pragma unroll
  for (int e = 0; e < E_NUM; ++e)
    for (int off = 32; off > 0; off >>= 1) acc[e] += __shfl_down(acc[e], off);
  __shared__ float part[4][E_NUM];
  if ((tid & 63) == 0) {
#pragma unroll
    for (int e = 0; e < E_NUM; ++e) part[tid >> 6][e] = acc[e];
  }
  __syncthreads();
  if (tid == 0) {
    float p[E_NUM];
    float mx = -1e30f;
    for (int e = 0; e < E_NUM; ++e) {
      p[e] = part[0][e] + part[1][e] + part[2][e] + part[3][e];
      mx = fmaxf(mx, p[e]);
    }
    float s = 0.f;
    for (int e = 0; e < E_NUM; ++e) { p[e] = __expf(p[e] - mx); s += p[e]; }
    const float invs = 1.f / s;
    for (int e = 0; e < E_NUM; ++e) p[e] *= invs;
    float gs[4];
    for (int g = 0; g < 4; ++g)
      gs[g] = fmaxf(fmaxf(p[4 * g], p[4 * g + 1]), fmaxf(p[4 * g + 2], p[4 * g + 3]));
    int g1 = 0;
    for (int g = 1; g < 4; ++g) if (gs[g] > gs[g1]) g1 = g;
    int g2 = -1;
    for (int g = 0; g < 4; ++g) {
      if (g == g1) continue;
      if (g2 < 0 || gs[g] > gs[g2]) g2 = g;
    }
    float m2[E_NUM], cw[E_NUM];
    for (int e = 0; e < E_NUM; ++e) {
      int g = e >> 2;
      m2[e] = (g == g1 || g == g2) ? p[e] : 0.f;
      cw[e] = 0.f;
    }
    float sum6 = 0.f;
    for (int k = 0; k < 6; ++k) {
      int bi = 0; float bv = -1.f;
      for (int e = 0; e < E_NUM; ++e)
        if (m2[e] > bv) { bv = m2[e]; bi = e; }
      cw[bi] = bv; sum6 += bv; m2[bi] = -2.f;
    }
    const float scale = 2.5f / sum6;
    for (int e = 0; e < E_NUM; ++e) comb[t * E_NUM + e] = cw[e] * scale;
  }
}

// ---------------- dispatch: per-expert ordered token lists (no atomics) ----------------
__global__ __launch_bounds__(256) void dispatch_k(const float* __restrict__ comb,
                                                  int* __restrict__ cnt,
                                                  int* __restrict__ tok) {
  const int e = blockIdx.x;          // 16 blocks
  const int tid = threadIdx.x;       // 256
  const int lane = tid & 63, wid = tid >> 6;
  __shared__ int wtot[4];
  int running = 0;
  for (int chunk = 0; chunk < T_TOK / 256; ++chunk) {
    const int t = chunk * 256 + tid;
    const bool sel = comb[t * E_NUM + e] > 0.f;
    unsigned long long mask = __ballot(sel);
    const int pre = __popcll(mask & ((1ull << lane) - 1ull));
    if (lane == 0) wtot[wid] = __popcll(mask);
    __syncthreads();
    int wbase = running;
    for (int w = 0; w < wid; ++w) wbase += wtot[w];
    if (sel) tok[e * T_TOK + wbase + pre] = t;
    running += wtot[0] + wtot[1] + wtot[2] + wtot[3];
    __syncthreads();
  }
  if (tid == 0) cnt[e] = running;
}

// ---------------- fused gate/up GEMM + silu*u*combine -> bf16 act ----------------
// Gathered A rows (token dispatch) when cnt/tok given; dense when null.
__global__ __launch_bounds__(256, 2) void gu_act_k(
    const u16* __restrict__ A, const u16* __restrict__ Bt,
    const float* __restrict__ comb, const int* __restrict__ cnt,
    const int* __restrict__ tok, u16* __restrict__ outp,
    int gu_off, long long bt_e_stride, long long out_e_stride, int out_stride) {
  const int e = blockIdx.z;
  const int M = cnt ? cnt[e] : T_TOK;
  const int m0 = blockIdx.y * 128;
  if (m0 >= M) return;
  __shared__ __align__(16) u16 As[128 * 64];
  __shared__ __align__(16) u16 Bg[64 * 64];
  __shared__ __align__(16) u16 Bu[64 * 64];
  __shared__ int tokS[128];

  const int n0 = blockIdx.x * 64;
  const u16* Bte = Bt + (size_t)e * bt_e_stride;
  const int tid = threadIdx.x;
  const int lane = tid & 63;
  const int wr = tid >> 7;
  const int wc = (tid >> 6) & 1;
  const int fr = lane & 15;
  const int fg = lane >> 4;

  if (tid < 128) {
    const int m = m0 + tid;
    tokS[tid] = tok ? tok[e * T_TOK + (m < M ? m : M - 1)] : m;
  }
  __syncthreads();

  const f32x4 zero = {0.f, 0.f, 0.f, 0.f};
  f32x4 accg[4][2], accu[4][2];
#pragma unroll
  for (int i = 0; i < 4; ++i)
#pragma unroll
    for (int j = 0; j < 2; ++j) { accg[i][j] = zero; accu[i][j] = zero; }

  for (int kt = 0; kt < H_DIM / 64; ++kt) {
    const int k0 = kt * 64;
    stage_gather<4>(A + k0, H_DIM, tokS, As, tid);
    stage_tile<2>(Bte + (size_t)n0 * H_DIM + k0, H_DIM, Bg, tid);
    stage_tile<2>(Bte + (size_t)(gu_off + n0) * H_DIM + k0, H_DIM, Bu, tid);
    __syncthreads();
#pragma unroll
    for (int kk = 0; kk < 2; ++kk) {
      const int kb = kk * 64 + fg * 16;
      bf16x8 af[4], bg[2], bu[2];
#pragma unroll
      for (int mi = 0; mi < 4; ++mi)
        af[mi] = *(const bf16x8*)lds_sw((char*)As, wr * 64 + mi * 16 + fr, kb);
#pragma unroll
      for (int ni = 0; ni < 2; ++ni) {
        bg[ni] = *(const bf16x8*)lds_sw((char*)Bg, wc * 32 + ni * 16 + fr, kb);
        bu[ni] = *(const bf16x8*)lds_sw((char*)Bu, wc * 32 + ni * 16 + fr, kb);
      }
#pragma unroll
      for (int mi = 0; mi < 4; ++mi)
#pragma unroll
        for (int ni = 0; ni < 2; ++ni) {
          accg[mi][ni] = MFMA(af[mi], bg[ni], accg[mi][ni]);
          accu[mi][ni] = MFMA(af[mi], bu[ni], accu[mi][ni]);
        }
    }
    __syncthreads();
  }

  const int colb = n0 + wc * 32;
#pragma unroll
  for (int mi = 0; mi < 4; ++mi) {
#pragma unroll
    for (int r = 0; r < 4; ++r) {
      const int ml = wr * 64 + mi * 16 + fg * 4 + r;
      if (m0 + ml >= M) continue;
      const float wgt = comb ? comb[tokS[ml] * E_NUM + e] : 1.0f;
      const size_t rowoff = (size_t)e * out_e_stride + (size_t)(m0 + ml) * out_stride;
#pragma unroll
      for (int ni = 0; ni < 2; ++ni) {
        float g = accg[mi][ni][r];
        float u = accu[mi][ni][r];
        float sg = g / (1.f + __expf(-g));
        outp[rowoff + colb + ni * 16 + fr] = f2bf(sg * u * wgt);
      }
    }
  }
}

// ---------------- shared-expert down: out = actS @ WsdT^T (plain writes) ----------------
__global__ __launch_bounds__(256, 2) void down_shared_k(
    const u16* __restrict__ A1, const u16* __restrict__ B1t,
    float* __restrict__ outp) {
  __shared__ __align__(16) u16 As[64 * 64];
  __shared__ __align__(16) u16 Bs[64 * 64];
  const int n0 = blockIdx.x * 64;
  const int m0 = blockIdx.y * 64;
  const int tid = threadIdx.x;
  const int lane = tid & 63;
  const int wr = tid >> 7, wc = (tid >> 6) & 1;
  const int fr = lane & 15, fg = lane >> 4;

  const f32x4 zero = {0.f, 0.f, 0.f, 0.f};
  f32x4 acc[2][2];
#pragma unroll
  for (int i = 0; i < 2; ++i)
#pragma unroll
    for (int j = 0; j < 2; ++j) acc[i][j] = zero;

  for (int kt = 0; kt < IS_DIM / 64; ++kt) {
    const int k0 = kt * 64;
    stage_tile<2>(A1 + (size_t)m0 * IS_DIM + k0, IS_DIM, As, tid);
    stage_tile<2>(B1t + (size_t)n0 * IS_DIM + k0, IS_DIM, Bs, tid);
    __syncthreads();
#pragma unroll
    for (int kk = 0; kk < 2; ++kk) {
      const int kb = kk * 64 + fg * 16;
      bf16x8 af[2], bfr[2];
#pragma unroll
      for (int mi = 0; mi < 2; ++mi)
        af[mi] = *(const bf16x8*)lds_sw((char*)As, wr * 32 + mi * 16 + fr, kb);
#pragma unroll
      for (int ni = 0; ni < 2; ++ni)
        bfr[ni] = *(const bf16x8*)lds_sw((char*)Bs, wc * 32 + ni * 16 + fr, kb);
#pragma unroll
      for (int mi = 0; mi < 2; ++mi)
#pragma unroll
        for (int ni = 0; ni < 2; ++ni) acc[mi][ni] = MFMA(af[mi], bfr[ni], acc[mi][ni]);
    }
    __syncthreads();
  }

#pragma unroll
  for (int mi = 0; mi < 2; ++mi)
#pragma unroll
    for (int r = 0; r < 4; ++r)
#pragma unroll
      for (int ni = 0; ni < 2; ++ni)
        outp[(size_t)(m0 + wr * 32 + mi * 16 + fg * 4 + r) * H_DIM + n0 + wc * 32 +
             ni * 16 + fr] = acc[mi][ni][r];
}

// ---------------- routed down: compact A rows, scatter-accumulate via atomicAdd ----------------
__global__ __launch_bounds__(256, 2) void down_routed_k(
    const u16* __restrict__ ACTC, const u16* __restrict__ WDT,
    const int* __restrict__ cnt, const int* __restrict__ tok,
    float* __restrict__ outp) {
  const int e = blockIdx.z;
  const int M = cnt[e];
  const int m0 = blockIdx.y * 64;
  if (m0 >= M) return;
  const int n0 = blockIdx.x * 64;
  __shared__ __align__(16) u16 As[64 * 64];
  __shared__ __align__(16) u16 Bs[64 * 64];
  __shared__ int tokS[64];
  const int tid = threadIdx.x;
  const int lane = tid & 63;
  const int wr = tid >> 7, wc = (tid >> 6) & 1;
  const int fr = lane & 15, fg = lane >> 4;
  if (tid < 64) tokS[tid] = tok[e * T_TOK + (m0 + tid < M ? m0 + tid : M - 1)];

  const u16* Ae = ACTC + (size_t)e * T_TOK * I_DIM;
  const u16* Be = WDT + (size_t)e * H_DIM * I_DIM;

  const f32x4 zero = {0.f, 0.f, 0.f, 0.f};
  f32x4 acc[2][2];
#pragma unroll
  for (int i = 0; i < 2; ++i)
#pragma unroll
    for (int j = 0; j < 2; ++j) acc[i][j] = zero;

  for (int kt = 0; kt < I_DIM / 64; ++kt) { // 11
    const int k0 = kt * 64;
    stage_tile<2>(Ae + (size_t)m0 * I_DIM + k0, I_DIM, As, tid);
    stage_tile<2>(Be + (size_t)n0 * I_DIM + k0, I_DIM, Bs, tid);
    __syncthreads();
#pragma unroll
    for (int kk = 0; kk < 2; ++kk) {
      const int kb = kk * 64 + fg * 16;
      bf16x8 af[2], bfr[2];
#pragma unroll
      for (int mi = 0; mi < 2; ++mi)
        af[mi] = *(const bf16x8*)lds_sw((char*)As, wr * 32 + mi * 16 + fr, kb);
#pragma unroll
      for (int ni = 0; ni < 2; ++ni)
        bfr[ni] = *(const bf16x8*)lds_sw((char*)Bs, wc * 32 + ni * 16 + fr, kb);
#pragma unroll
      for (int mi = 0; mi < 2; ++mi)
#pragma unroll
        for (int ni = 0; ni < 2; ++ni) acc[mi][ni] = MFMA(af[mi], bfr[ni], acc[mi][ni]);
    }
    __syncthreads();
  }

#pragma unroll
  for (int mi = 0; mi < 2; ++mi) {
#pragma unroll
    for (int r = 0; r < 4; ++r) {
      const int ml = wr * 32 + mi * 16 + fg * 4 + r;
      if (m0 + ml >= M) continue;
      const int t = tokS[ml];
#pragma unroll
      for (int ni = 0; ni < 2; ++ni)
        atomicAdd(&outp[(size_t)t * H_DIM + n0 + wc * 32 + ni * 16 + fr],
                  acc[mi][ni][r]);
    }
  }
}

extern "C" void kernel_launch(void* const* d_in, const int* in_sizes, int n_in,
                              void* d_out, int out_size, void* d_ws, size_t ws_size,
                              hipStream_t stream) {
  const float* x    = (const float*)d_in[0];
  const float* wg   = (const float*)d_in[1];
  const float* wgu  = (const float*)d_in[2];
  const float* wd   = (const float*)d_in[3];
  const float* wsgu = (const float*)d_in[4];
  const float* wsd  = (const float*)d_in[5];
  float* out = (float*)d_out;

  char* ws = (char*)d_ws;
  size_t off = 0;
  auto alloc = [&](size_t b) { size_t r = off; off += (b + 255) & ~(size_t)255; return r; };
  u16*   XB    = (u16*)  (ws + alloc((size_t)T_TOK * H_DIM * 2));
  float* COMB  = (float*)(ws + alloc((size_t)T_TOK * E_NUM * 4));
  int*   CNT   = (int*)  (ws + alloc((size_t)E_NUM * 4));
  int*   TOK   = (int*)  (ws + alloc((size_t)E_NUM * T_TOK * 4));
  u16*   WGUT  = (u16*)  (ws + alloc((size_t)E_NUM * 2 * I_DIM * H_DIM * 2)); // [e][1408][2048]
  u16*   WDT   = (u16*)  (ws + alloc((size_t)E_NUM * H_DIM * I_DIM * 2));     // [e][2048][704]
  u16*   WSGUT = (u16*)  (ws + alloc((size_t)2 * IS_DIM * H_DIM * 2));        // [2816][2048]
  u16*   WSDT  = (u16*)  (ws + alloc((size_t)H_DIM * IS_DIM * 2));            // [2048][1408]
  u16*   ACTC  = (u16*)  (ws + alloc((size_t)E_NUM * T_TOK * I_DIM * 2));     // [e][1024][704]
  u16*   ACTS  = (u16*)  (ws + alloc((size_t)T_TOK * IS_DIM * 2));            // [1024][1408]
  if (ws_size < off) return;

  conv_x_k<<<(T_TOK * H_DIM) / (256 * 8), 256, 0, stream>>>(x, XB);
  router_k<<<T_TOK, 256, 0, stream>>>(x, wg, COMB);
  dispatch_k<<<E_NUM, 256, 0, stream>>>(COMB, CNT, TOK);
  transp_k<<<dim3(44, 64, 16), dim3(32, 8), 0, stream>>>(wgu, WGUT, H_DIM, 2 * I_DIM);
  transp_k<<<dim3(64, 22, 16), dim3(32, 8), 0, stream>>>(wd, WDT, I_DIM, H_DIM);
  transp_k<<<dim3(88, 64, 1), dim3(32, 8), 0, stream>>>(wsgu, WSGUT, H_DIM, 2 * IS_DIM);
  transp_k<<<dim3(64, 44, 1), dim3(32, 8), 0, stream>>>(wsd, WSDT, IS_DIM, H_DIM);
  // routed gate/up on dispatched tokens -> compact act [e][row][704]
  gu_act_k<<<dim3(I_DIM / 64, T_TOK / 128, E_NUM), 256, 0, stream>>>(
      XB, WGUT, COMB, CNT, TOK, ACTC, I_DIM, (long long)(2 * I_DIM) * H_DIM,
      (long long)T_TOK * I_DIM, I_DIM);
  // shared gate/up (dense)
  gu_act_k<<<dim3(IS_DIM / 64, T_TOK / 128, 1), 256, 0, stream>>>(
      XB, WSGUT, nullptr, nullptr, nullptr, ACTS, IS_DIM, 0, 0, IS_DIM);
  // shared down writes out, then routed down accumulates atomically
  down_shared_k<<<dim3(H_DIM / 64, T_TOK / 64), 256, 0, stream>>>(ACTS, WSDT, out);
  down_routed_k<<<dim3(H_DIM / 64, T_TOK / 64, E_NUM), 256, 0, stream>>>(
      ACTC, WDT, CNT, TOK, out);
}

// Round 3
// 319.446 us; speedup vs baseline: 1.3446x; 1.0239x over previous
//
#include <hip/hip_runtime.h>

typedef unsigned short u16;
typedef u16 u16x8 __attribute__((ext_vector_type(8)));
typedef __bf16 bf16x8 __attribute__((ext_vector_type(8)));
typedef float f32x4 __attribute__((ext_vector_type(4)));

#define T_TOK 1024
#define H_DIM 2048
#define E_NUM 16
#define I_DIM 704
#define IS_DIM 1408

#define MFMA(a, b, c) __builtin_amdgcn_mfma_f32_16x16x32_bf16(a, b, c, 0, 0, 0)

__device__ __forceinline__ u16 f2bf(float f) {
  union { float f; unsigned u; } v; v.f = f;
  unsigned r = v.u + 0x7fffu + ((v.u >> 16) & 1u);
  return (u16)(r >> 16);
}

// async global->LDS 16B per lane; dest linear (wave-uniform base + lane*16)
__device__ __forceinline__ void gload16(const void* g, void* l) {
  __builtin_amdgcn_global_load_lds(
      (const __attribute__((address_space(1))) unsigned int*)g,
      (__attribute__((address_space(3))) unsigned int*)l, 16, 0, 0);
}

// Swizzled LDS read address within 128-byte rows: XOR bits[6:4] with (row&7).
// Staging pre-swizzles the per-lane GLOBAL source so linear LDS holds this layout.
__device__ __forceinline__ const char* lds_sw(const u16* base, int row, int kByte) {
  return (const char*)base + row * 128 + (kByte ^ ((row & 7) << 4));
}

// ---------------- x fp32 -> bf16 ----------------
__global__ __launch_bounds__(256) void conv_x_k(const float* __restrict__ in,
                                                u16* __restrict__ outp) {
  const int i = (blockIdx.x * 256 + threadIdx.x) * 8;
  f32x4 a = *(const f32x4*)(in + i);
  f32x4 b = *(const f32x4*)(in + i + 4);
  u16x8 o;
  o[0] = f2bf(a[0]); o[1] = f2bf(a[1]); o[2] = f2bf(a[2]); o[3] = f2bf(a[3]);
  o[4] = f2bf(b[0]); o[5] = f2bf(b[1]); o[6] = f2bf(b[2]); o[7] = f2bf(b[3]);
  *(u16x8*)(outp + i) = o;
}

// ---------------- transpose + convert: [R][C] f32 -> [C][R] bf16 ----------------
// Tile TR rows x 64 cols; writes paired bf16 (u32) -> 256B/wave stores.
template <int TR>
__global__ __launch_bounds__(256) void transp_k(const float* __restrict__ in,
                                                u16* __restrict__ outp, int R, int C) {
  __shared__ float tile[TR][65];
  const size_t base = (size_t)blockIdx.z * (size_t)R * C;
  const int c0 = blockIdx.x * 64, r0 = blockIdx.y * TR;
  const int tid = threadIdx.x;
  const int col = tid & 63, rq = tid >> 6;
#pragma unroll
  for (int i = 0; i < TR / 4; ++i) {
    const int row = i * 4 + rq;
    tile[row][col] = in[base + (size_t)(r0 + row) * C + c0 + col];
  }
  __syncthreads();
#pragma unroll
  for (int i = 0; i < TR / 8; ++i) {
    const int idx = i * 256 + tid;
    const int oc = idx / (TR / 2), pr = idx % (TR / 2);
    const unsigned lo = f2bf(tile[2 * pr][oc]);
    const unsigned hi = f2bf(tile[2 * pr + 1][oc]);
    *(unsigned*)&outp[base + (size_t)(c0 + oc) * R + r0 + 2 * pr] = lo | (hi << 16);
  }
}

// ---------------- router ----------------
__global__ __launch_bounds__(256) void router_k(const float* __restrict__ x,
                                                const float* __restrict__ wg,
                                                float* __restrict__ comb) {
  const int t = blockIdx.x;
  const int tid = threadIdx.x;
  float acc[E_NUM];
#pragma unroll
  for (int e = 0; e < E_NUM; ++e) acc[e] = 0.f;
  const float* xr = x + (size_t)t * H_DIM;
  for (int h = tid; h < H_DIM; h += 256) {
    const float xv = xr[h];
    const f32x4* wr = (const f32x4*)(wg + (size_t)h * E_NUM);
#pragma unroll
    for (int q = 0; q < 4; ++q) {
      f32x4 w4 = wr[q];
      acc[q * 4 + 0] += xv * w4[0];
      acc[q * 4 + 1] += xv * w4[1];
      acc[q * 4 + 2] += xv * w4[2];
      acc[q * 4 + 3] += xv * w4[3];
    }
  }
#pragma unroll
  for (int e = 0; e < E_NUM; ++e)
    for (int off = 32; off > 0; off >>= 1) acc[e] += __shfl_down(acc[e], off);
  __shared__ float part[4][E_NUM];
  if ((tid & 63) == 0) {
#pragma unroll
    for (int e = 0; e < E_NUM; ++e) part[tid >> 6][e] = acc[e];
  }
  __syncthreads();
  if (tid == 0) {
    float p[E_NUM];
    float mx = -1e30f;
    for (int e = 0; e < E_NUM; ++e) {
      p[e] = part[0][e] + part[1][e] + part[2][e] + part[3][e];
      mx = fmaxf(mx, p[e]);
    }
    float s = 0.f;
    for (int e = 0; e < E_NUM; ++e) { p[e] = __expf(p[e] - mx); s += p[e]; }
    const float invs = 1.f / s;
    for (int e = 0; e < E_NUM; ++e) p[e] *= invs;
    float gs[4];
    for (int g = 0; g < 4; ++g)
      gs[g] = fmaxf(fmaxf(p[4 * g], p[4 * g + 1]), fmaxf(p[4 * g + 2], p[4 * g + 3]));
    int g1 = 0;
    for (int g = 1; g < 4; ++g) if (gs[g] > gs[g1]) g1 = g;
    int g2 = -1;
    for (int g = 0; g < 4; ++g) {
      if (g == g1) continue;
      if (g2 < 0 || gs[g] > gs[g2]) g2 = g;
    }
    float m2[E_NUM], cw[E_NUM];
    for (int e = 0; e < E_NUM; ++e) {
      int g = e >> 2;
      m2[e] = (g == g1 || g == g2) ? p[e] : 0.f;
      cw[e] = 0.f;
    }
    float sum6 = 0.f;
    for (int k = 0; k < 6; ++k) {
      int bi = 0; float bv = -1.f;
      for (int e = 0; e < E_NUM; ++e)
        if (m2[e] > bv) { bv = m2[e]; bi = e; }
      cw[bi] = bv; sum6 += bv; m2[bi] = -2.f;
    }
    const float scale = 2.5f / sum6;
    for (int e = 0; e < E_NUM; ++e) comb[t * E_NUM + e] = cw[e] * scale;
  }
}

// ---------------- dispatch: per-expert ordered token lists (no atomics) ----------------
__global__ __launch_bounds__(256) void dispatch_k(const float* __restrict__ comb,
                                                  int* __restrict__ cnt,
                                                  int* __restrict__ tok) {
  const int e = blockIdx.x;
  const int tid = threadIdx.x;
  const int lane = tid & 63, wid = tid >> 6;
  __shared__ int wtot[4];
  int running = 0;
  for (int chunk = 0; chunk < T_TOK / 256; ++chunk) {
    const int t = chunk * 256 + tid;
    const bool sel = comb[t * E_NUM + e] > 0.f;
    unsigned long long mask = __ballot(sel);
    const int pre = __popcll(mask & ((1ull << lane) - 1ull));
    if (lane == 0) wtot[wid] = __popcll(mask);
    __syncthreads();
    int wbase = running;
    for (int w = 0; w < wid; ++w) wbase += wtot[w];
    if (sel) tok[e * T_TOK + wbase + pre] = t;
    running += wtot[0] + wtot[1] + wtot[2] + wtot[3];
    __syncthreads();
  }
  if (tid == 0) cnt[e] = running;
}

// ---------------- fused gate/up GEMM + silu*u*combine -> bf16 act ----------------
// BM=128, BN=64 (g and u tiles). global_load_lds staging, double-buffered,
// one barrier per K-tile. A rows gathered via per-lane global addresses.
__global__ __launch_bounds__(256, 2) void gu_act_k(
    const u16* __restrict__ A, const u16* __restrict__ Bt,
    const float* __restrict__ comb, const int* __restrict__ cnt,
    const int* __restrict__ tok, u16* __restrict__ outp,
    int gu_off, long long bt_e_stride, long long out_e_stride, int out_stride) {
  const int e = blockIdx.z;
  const int M = cnt ? cnt[e] : T_TOK;
  const int m0 = blockIdx.y * 128;
  if (m0 >= M) return;
  __shared__ __align__(16) u16 S[32768]; // As dbuf 2x8192, Bg 2x4096, Bu 2x4096
  __shared__ int tokS[128];

  const int n0 = blockIdx.x * 64;
  const u16* Bte = Bt + (size_t)e * bt_e_stride;
  const u16* Bgp = Bte + (size_t)n0 * H_DIM;
  const u16* Bup = Bte + (size_t)(gu_off + n0) * H_DIM;
  const int tid = threadIdx.x;
  const int w = tid >> 6, l = tid & 63;
  const int r8 = l >> 3;
  const int sk = ((l & 7) ^ r8) * 8; // inverse-swizzled source k offset (elems)

  if (tid < 128) {
    const int m = m0 + tid;
    const int mc = m < M ? m : M - 1;
    tokS[tid] = tok ? tok[e * T_TOK + mc] : mc;
  }
  size_t arow[4];
#pragma unroll
  for (int j = 0; j < 4; ++j) {
    const int m = m0 + w * 32 + j * 8 + r8;
    const int mc = m < M ? m : M - 1;
    const int t = tok ? tok[e * T_TOK + mc] : mc;
    arow[j] = (size_t)t * H_DIM + sk;
  }

  auto STAGE = [&](int kt, int cur) {
    const int k0 = kt * 64;
    u16* AsC = S + cur * 8192;
    u16* BgC = S + 16384 + cur * 4096;
    u16* BuC = S + 24576 + cur * 4096;
#pragma unroll
    for (int j = 0; j < 4; ++j)
      gload16(A + arow[j] + k0, AsC + (w * 4 + j) * 512);
#pragma unroll
    for (int j = 0; j < 2; ++j) {
      const size_t br = (size_t)(w * 16 + j * 8 + r8) * H_DIM + sk + k0;
      gload16(Bgp + br, BgC + (w * 2 + j) * 512);
      gload16(Bup + br, BuC + (w * 2 + j) * 512);
    }
  };

  const int wr = tid >> 7;
  const int wc = (tid >> 6) & 1;
  const int fr = l & 15;
  const int fg = l >> 4;

  const f32x4 zero = {0.f, 0.f, 0.f, 0.f};
  f32x4 accg[4][2], accu[4][2];
#pragma unroll
  for (int i = 0; i < 4; ++i)
#pragma unroll
    for (int j = 0; j < 2; ++j) { accg[i][j] = zero; accu[i][j] = zero; }

  STAGE(0, 0);
  __syncthreads();
  int cur = 0;
  for (int kt = 0; kt < H_DIM / 64; ++kt) {
    if (kt + 1 < H_DIM / 64) STAGE(kt + 1, cur ^ 1);
    const u16* AsC = S + cur * 8192;
    const u16* BgC = S + 16384 + cur * 4096;
    const u16* BuC = S + 24576 + cur * 4096;
#pragma unroll
    for (int kk = 0; kk < 2; ++kk) {
      const int kb = kk * 64 + fg * 16;
      bf16x8 af[4], bg[2], bu[2];
#pragma unroll
      for (int mi = 0; mi < 4; ++mi)
        af[mi] = *(const bf16x8*)lds_sw(AsC, wr * 64 + mi * 16 + fr, kb);
#pragma unroll
      for (int ni = 0; ni < 2; ++ni) {
        bg[ni] = *(const bf16x8*)lds_sw(BgC, wc * 32 + ni * 16 + fr, kb);
        bu[ni] = *(const bf16x8*)lds_sw(BuC, wc * 32 + ni * 16 + fr, kb);
      }
#pragma unroll
      for (int mi = 0; mi < 4; ++mi)
#pragma unroll
        for (int ni = 0; ni < 2; ++ni) {
          accg[mi][ni] = MFMA(af[mi], bg[ni], accg[mi][ni]);
          accu[mi][ni] = MFMA(af[mi], bu[ni], accu[mi][ni]);
        }
    }
    __syncthreads();
    cur ^= 1;
  }

  const int colb = n0 + wc * 32;
#pragma unroll
  for (int mi = 0; mi < 4; ++mi) {
#pragma unroll
    for (int r = 0; r < 4; ++r) {
      const int ml = wr * 64 + mi * 16 + fg * 4 + r;
      if (m0 + ml >= M) continue;
      const float wgt = comb ? comb[tokS[ml] * E_NUM + e] : 1.0f;
      const size_t rowoff = (size_t)e * out_e_stride + (size_t)(m0 + ml) * out_stride;
#pragma unroll
      for (int ni = 0; ni < 2; ++ni) {
        float g = accg[mi][ni][r];
        float u = accu[mi][ni][r];
        float sg = g / (1.f + __expf(-g));
        outp[rowoff + colb + ni * 16 + fr] = f2bf(sg * u * wgt);
      }
    }
  }
}

// ---------------- down GEMM core: BM=64, BN=128, dbuf global_load_lds ----------------
// Each wave covers all 64 m rows x 32 n cols. acc[4][2].
template <bool ATOMIC>
__device__ __forceinline__ void down_core(
    const u16* __restrict__ Ap, int astride, // A rows at m0 (compact), stride K
    const u16* __restrict__ Bp, int bstride, // B rows at n0, stride K
    int NT, int M, int m0, int n0, const int* tokS, float* __restrict__ outp) {
  __shared__ __align__(16) u16 S[24576]; // As 2x4096, Bs 2x8192
  const int tid = threadIdx.x;
  const int w = tid >> 6, l = tid & 63;
  const int r8 = l >> 3;
  const int sk = ((l & 7) ^ r8) * 8;

  size_t arow[2];
#pragma unroll
  for (int j = 0; j < 2; ++j) {
    const int m = w * 16 + j * 8 + r8;
    arow[j] = (size_t)(m0 + m < M ? m : (M - 1 - m0 > 0 ? M - 1 - m0 : 0)) * astride + sk;
  }
  size_t brow[4];
#pragma unroll
  for (int j = 0; j < 4; ++j)
    brow[j] = (size_t)(w * 32 + j * 8 + r8) * bstride + sk;

  auto STAGE = [&](int kt, int cur) {
    const int k0 = kt * 64;
    u16* AsC = S + cur * 4096;
    u16* BsC = S + 8192 + cur * 8192;
#pragma unroll
    for (int j = 0; j < 2; ++j)
      gload16(Ap + arow[j] + k0, AsC + (w * 2 + j) * 512);
#pragma unroll
    for (int j = 0; j < 4; ++j)
      gload16(Bp + brow[j] + k0, BsC + (w * 4 + j) * 512);
  };

  const int fr = l & 15, fg = l >> 4;
  const f32x4 zero = {0.f, 0.f, 0.f, 0.f};
  f32x4 acc[4][2];
#pragma unroll
  for (int i = 0; i < 4; ++i)
#pragma unroll
    for (int j = 0; j < 2; ++j) acc[i][j] = zero;

  STAGE(0, 0);
  __syncthreads();
  int cur = 0;
  for (int kt = 0; kt < NT; ++kt) {
    if (kt + 1 < NT) STAGE(kt + 1, cur ^ 1);
    const u16* AsC = S + cur * 4096;
    const u16* BsC = S + 8192 + cur * 8192;
#pragma unroll
    for (int kk = 0; kk < 2; ++kk) {
      const int kb = kk * 64 + fg * 16;
      bf16x8 af[4], bfr[2];
#pragma unroll
      for (int mi = 0; mi < 4; ++mi)
        af[mi] = *(const bf16x8*)lds_sw(AsC, mi * 16 + fr, kb);
#pragma unroll
      for (int ni = 0; ni < 2; ++ni)
        bfr[ni] = *(const bf16x8*)lds_sw(BsC, w * 32 + ni * 16 + fr, kb);
#pragma unroll
      for (int mi = 0; mi < 4; ++mi)
#pragma unroll
        for (int ni = 0; ni < 2; ++ni) acc[mi][ni] = MFMA(af[mi], bfr[ni], acc[mi][ni]);
    }
    __syncthreads();
    cur ^= 1;
  }

#pragma unroll
  for (int mi = 0; mi < 4; ++mi) {
#pragma unroll
    for (int r = 0; r < 4; ++r) {
      const int ml = mi * 16 + fg * 4 + r;
      if (m0 + ml >= M) continue;
      const int trow = ATOMIC ? tokS[ml] : (m0 + ml);
      float* op = outp + (size_t)trow * H_DIM + n0 + w * 32;
#pragma unroll
      for (int ni = 0; ni < 2; ++ni) {
        if (ATOMIC)
          atomicAdd(op + ni * 16 + fr, acc[mi][ni][r]);
        else
          op[ni * 16 + fr] = acc[mi][ni][r];
      }
    }
  }
}

__global__ __launch_bounds__(256, 3) void down_shared_k(
    const u16* __restrict__ A1, const u16* __restrict__ B1t, float* __restrict__ outp) {
  const int n0 = blockIdx.x * 128, m0 = blockIdx.y * 64;
  down_core<false>(A1 + (size_t)m0 * IS_DIM, IS_DIM, B1t + (size_t)n0 * IS_DIM, IS_DIM,
                   IS_DIM / 64, T_TOK, m0, n0, nullptr, outp);
}

__global__ __launch_bounds__(256, 3) void down_routed_k(
    const u16* __restrict__ ACTC, const u16* __restrict__ WDT,
    const int* __restrict__ cnt, const int* __restrict__ tok, float* __restrict__ outp) {
  const int e = blockIdx.z;
  const int M = cnt[e];
  const int m0 = blockIdx.y * 64;
  if (m0 >= M) return;
  const int n0 = blockIdx.x * 128;
  __shared__ int tokS[64];
  const int tid = threadIdx.x;
  if (tid < 64) tokS[tid] = tok[e * T_TOK + (m0 + tid < M ? m0 + tid : M - 1)];
  __syncthreads();
  down_core<true>(ACTC + ((size_t)e * T_TOK + m0) * I_DIM, I_DIM,
                  WDT + ((size_t)e * H_DIM + n0) * I_DIM, I_DIM,
                  I_DIM / 64, M, m0, n0, tokS, outp);
}

extern "C" void kernel_launch(void* const* d_in, const int* in_sizes, int n_in,
                              void* d_out, int out_size, void* d_ws, size_t ws_size,
                              hipStream_t stream) {
  const float* x    = (const float*)d_in[0];
  const float* wg   = (const float*)d_in[1];
  const float* wgu  = (const float*)d_in[2];
  const float* wd   = (const float*)d_in[3];
  const float* wsgu = (const float*)d_in[4];
  const float* wsd  = (const float*)d_in[5];
  float* out = (float*)d_out;

  char* ws = (char*)d_ws;
  size_t off = 0;
  auto alloc = [&](size_t b) { size_t r = off; off += (b + 255) & ~(size_t)255; return r; };
  u16*   XB    = (u16*)  (ws + alloc((size_t)T_TOK * H_DIM * 2));
  float* COMB  = (float*)(ws + alloc((size_t)T_TOK * E_NUM * 4));
  int*   CNT   = (int*)  (ws + alloc((size_t)E_NUM * 4));
  int*   TOK   = (int*)  (ws + alloc((size_t)E_NUM * T_TOK * 4));
  u16*   WGUT  = (u16*)  (ws + alloc((size_t)E_NUM * 2 * I_DIM * H_DIM * 2)); // [e][1408][2048]
  u16*   WDT   = (u16*)  (ws + alloc((size_t)E_NUM * H_DIM * I_DIM * 2));     // [e][2048][704]
  u16*   WSGUT = (u16*)  (ws + alloc((size_t)2 * IS_DIM * H_DIM * 2));        // [2816][2048]
  u16*   WSDT  = (u16*)  (ws + alloc((size_t)H_DIM * IS_DIM * 2));            // [2048][1408]
  u16*   ACTC  = (u16*)  (ws + alloc((size_t)E_NUM * T_TOK * I_DIM * 2));     // [e][1024][704]
  u16*   ACTS  = (u16*)  (ws + alloc((size_t)T_TOK * IS_DIM * 2));            // [1024][1408]
  if (ws_size < off) return;

  conv_x_k<<<(T_TOK * H_DIM) / (256 * 8), 256, 0, stream>>>(x, XB);
  router_k<<<T_TOK, 256, 0, stream>>>(x, wg, COMB);
  dispatch_k<<<E_NUM, 256, 0, stream>>>(COMB, CNT, TOK);
  // weight transposes fp32 -> bf16 [N][K]
  transp_k<128><<<dim3(22, 16, 16), 256, 0, stream>>>(wgu, WGUT, H_DIM, 2 * I_DIM);
  transp_k<64><<<dim3(32, 11, 16), 256, 0, stream>>>(wd, WDT, I_DIM, H_DIM);
  transp_k<128><<<dim3(44, 16, 1), 256, 0, stream>>>(wsgu, WSGUT, H_DIM, 2 * IS_DIM);
  transp_k<128><<<dim3(32, 11, 1), 256, 0, stream>>>(wsd, WSDT, IS_DIM, H_DIM);
  // routed gate/up on dispatched tokens -> compact act [e][row][704]
  gu_act_k<<<dim3(I_DIM / 64, T_TOK / 128, E_NUM), 256, 0, stream>>>(
      XB, WGUT, COMB, CNT, TOK, ACTC, I_DIM, (long long)(2 * I_DIM) * H_DIM,
      (long long)T_TOK * I_DIM, I_DIM);
  // shared gate/up (dense)
  gu_act_k<<<dim3(IS_DIM / 64, T_TOK / 128, 1), 256, 0, stream>>>(
      XB, WSGUT, nullptr, nullptr, nullptr, ACTS, IS_DIM, 0, 0, IS_DIM);
  // shared down writes out, then routed down accumulates atomically
  down_shared_k<<<dim3(H_DIM / 128, T_TOK / 64), 256, 0, stream>>>(ACTS, WSDT, out);
  down_routed_k<<<dim3(H_DIM / 128, T_TOK / 64, E_NUM), 256, 0, stream>>>(
      ACTC, WDT, CNT, TOK, out);
}

// Round 4
// 298.968 us; speedup vs baseline: 1.4367x; 1.0685x over previous
//
#include <hip/hip_runtime.h>

typedef unsigned short u16;
typedef u16 u16x8 __attribute__((ext_vector_type(8)));
typedef __bf16 bf16x8 __attribute__((ext_vector_type(8)));
typedef float f32x4 __attribute__((ext_vector_type(4)));

#define T_TOK 1024
#define H_DIM 2048
#define E_NUM 16
#define I_DIM 704
#define IS_DIM 1408

#define MFMA(a, b, c) __builtin_amdgcn_mfma_f32_16x16x32_bf16(a, b, c, 0, 0, 0)

__device__ __forceinline__ u16 f2bf(float f) {
  union { float f; unsigned u; } v; v.f = f;
  unsigned r = v.u + 0x7fffu + ((v.u >> 16) & 1u);
  return (u16)(r >> 16);
}

// async global->LDS 16B per lane; dest linear (wave-uniform base + lane*16)
__device__ __forceinline__ void gload16(const void* g, void* l) {
  __builtin_amdgcn_global_load_lds(
      (const __attribute__((address_space(1))) unsigned int*)g,
      (__attribute__((address_space(3))) unsigned int*)l, 16, 0, 0);
}

// Swizzled LDS read address within 128-byte rows: XOR bits[6:4] with (row&7).
// Staging pre-swizzles the per-lane GLOBAL source so linear LDS holds this layout.
__device__ __forceinline__ const char* lds_sw(const u16* base, int row, int kByte) {
  return (const char*)base + row * 128 + (kByte ^ ((row & 7) << 4));
}

// ---------------- x fp32 -> bf16 ----------------
__global__ __launch_bounds__(256) void conv_x_k(const float* __restrict__ in,
                                                u16* __restrict__ outp) {
  const int i = (blockIdx.x * 256 + threadIdx.x) * 8;
  f32x4 a = *(const f32x4*)(in + i);
  f32x4 b = *(const f32x4*)(in + i + 4);
  u16x8 o;
  o[0] = f2bf(a[0]); o[1] = f2bf(a[1]); o[2] = f2bf(a[2]); o[3] = f2bf(a[3]);
  o[4] = f2bf(b[0]); o[5] = f2bf(b[1]); o[6] = f2bf(b[2]); o[7] = f2bf(b[3]);
  *(u16x8*)(outp + i) = o;
}

// ---------------- transpose + convert: [R][C] f32 -> [C][R] bf16 ----------------
template <int TR>
__global__ __launch_bounds__(256) void transp_k(const float* __restrict__ in,
                                                u16* __restrict__ outp, int R, int C) {
  __shared__ float tile[TR][65];
  const size_t base = (size_t)blockIdx.z * (size_t)R * C;
  const int c0 = blockIdx.x * 64, r0 = blockIdx.y * TR;
  const int tid = threadIdx.x;
  const int col = tid & 63, rq = tid >> 6;
#pragma unroll
  for (int i = 0; i < TR / 4; ++i) {
    const int row = i * 4 + rq;
    tile[row][col] = in[base + (size_t)(r0 + row) * C + c0 + col];
  }
  __syncthreads();
#pragma unroll
  for (int i = 0; i < TR / 8; ++i) {
    const int idx = i * 256 + tid;
    const int oc = idx / (TR / 2), pr = idx % (TR / 2);
    const unsigned lo = f2bf(tile[2 * pr][oc]);
    const unsigned hi = f2bf(tile[2 * pr + 1][oc]);
    *(unsigned*)&outp[base + (size_t)(c0 + oc) * R + r0 + 2 * pr] = lo | (hi << 16);
  }
}

// ---------------- router ----------------
__global__ __launch_bounds__(256) void router_k(const float* __restrict__ x,
                                                const float* __restrict__ wg,
                                                float* __restrict__ comb) {
  const int t = blockIdx.x;
  const int tid = threadIdx.x;
  float acc[E_NUM];
#pragma unroll
  for (int e = 0; e < E_NUM; ++e) acc[e] = 0.f;
  const float* xr = x + (size_t)t * H_DIM;
  for (int h = tid; h < H_DIM; h += 256) {
    const float xv = xr[h];
    const f32x4* wr = (const f32x4*)(wg + (size_t)h * E_NUM);
#pragma unroll
    for (int q = 0; q < 4; ++q) {
      f32x4 w4 = wr[q];
      acc[q * 4 + 0] += xv * w4[0];
      acc[q * 4 + 1] += xv * w4[1];
      acc[q * 4 + 2] += xv * w4[2];
      acc[q * 4 + 3] += xv * w4[3];
    }
  }
#pragma unroll
  for (int e = 0; e < E_NUM; ++e)
    for (int off = 32; off > 0; off >>= 1) acc[e] += __shfl_down(acc[e], off);
  __shared__ float part[4][E_NUM];
  if ((tid & 63) == 0) {
#pragma unroll
    for (int e = 0; e < E_NUM; ++e) part[tid >> 6][e] = acc[e];
  }
  __syncthreads();
  if (tid == 0) {
    float p[E_NUM];
    float mx = -1e30f;
    for (int e = 0; e < E_NUM; ++e) {
      p[e] = part[0][e] + part[1][e] + part[2][e] + part[3][e];
      mx = fmaxf(mx, p[e]);
    }
    float s = 0.f;
    for (int e = 0; e < E_NUM; ++e) { p[e] = __expf(p[e] - mx); s += p[e]; }
    const float invs = 1.f / s;
    for (int e = 0; e < E_NUM; ++e) p[e] *= invs;
    float gs[4];
    for (int g = 0; g < 4; ++g)
      gs[g] = fmaxf(fmaxf(p[4 * g], p[4 * g + 1]), fmaxf(p[4 * g + 2], p[4 * g + 3]));
    int g1 = 0;
    for (int g = 1; g < 4; ++g) if (gs[g] > gs[g1]) g1 = g;
    int g2 = -1;
    for (int g = 0; g < 4; ++g) {
      if (g == g1) continue;
      if (g2 < 0 || gs[g] > gs[g2]) g2 = g;
    }
    float m2[E_NUM], cw[E_NUM];
    for (int e = 0; e < E_NUM; ++e) {
      int g = e >> 2;
      m2[e] = (g == g1 || g == g2) ? p[e] : 0.f;
      cw[e] = 0.f;
    }
    float sum6 = 0.f;
    for (int k = 0; k < 6; ++k) {
      int bi = 0; float bv = -1.f;
      for (int e = 0; e < E_NUM; ++e)
        if (m2[e] > bv) { bv = m2[e]; bi = e; }
      cw[bi] = bv; sum6 += bv; m2[bi] = -2.f;
    }
    const float scale = 2.5f / sum6;
    for (int e = 0; e < E_NUM; ++e) comb[t * E_NUM + e] = cw[e] * scale;
  }
}

// ---------------- dispatch: per-expert ordered token lists (no atomics) ----------------
__global__ __launch_bounds__(256) void dispatch_k(const float* __restrict__ comb,
                                                  int* __restrict__ cnt,
                                                  int* __restrict__ tok) {
  const int e = blockIdx.x;
  const int tid = threadIdx.x;
  const int lane = tid & 63, wid = tid >> 6;
  __shared__ int wtot[4];
  int running = 0;
  for (int chunk = 0; chunk < T_TOK / 256; ++chunk) {
    const int t = chunk * 256 + tid;
    const bool sel = comb[t * E_NUM + e] > 0.f;
    unsigned long long mask = __ballot(sel);
    const int pre = __popcll(mask & ((1ull << lane) - 1ull));
    if (lane == 0) wtot[wid] = __popcll(mask);
    __syncthreads();
    int wbase = running;
    for (int w = 0; w < wid; ++w) wbase += wtot[w];
    if (sel) tok[e * T_TOK + wbase + pre] = t;
    running += wtot[0] + wtot[1] + wtot[2] + wtot[3];
    __syncthreads();
  }
  if (tid == 0) cnt[e] = running;
}

// ---------------- fused gate/up GEMM + silu*u*combine -> bf16 act ----------------
// m97 structure: single-buffered global_load_lds staging, STAGE -> sync ->
// compute -> sync. 32.5 KB LDS -> 4 blocks/CU; cross-block wave overlap
// hides the barrier drain (m114).
__global__ __launch_bounds__(256, 4) void gu_act_k(
    const u16* __restrict__ A, const u16* __restrict__ Bt,
    const float* __restrict__ comb, const int* __restrict__ cnt,
    const int* __restrict__ tok, u16* __restrict__ outp,
    int gu_off, long long bt_e_stride, long long out_e_stride, int out_stride) {
  const int e = blockIdx.z;
  const int M = cnt ? cnt[e] : T_TOK;
  const int m0 = blockIdx.y * 128;
  if (m0 >= M) return;
  __shared__ __align__(16) u16 S[16384]; // As 8192, Bg 4096, Bu 4096
  __shared__ int tokS[128];

  const int n0 = blockIdx.x * 64;
  const u16* Bte = Bt + (size_t)e * bt_e_stride;
  const u16* Bgp = Bte + (size_t)n0 * H_DIM;
  const u16* Bup = Bte + (size_t)(gu_off + n0) * H_DIM;
  const int tid = threadIdx.x;
  const int w = tid >> 6, l = tid & 63;
  const int r8 = l >> 3;
  const int sk = ((l & 7) ^ r8) * 8; // inverse-swizzled source k offset (elems)

  if (tid < 128) {
    const int m = m0 + tid;
    const int mc = m < M ? m : M - 1;
    tokS[tid] = tok ? tok[e * T_TOK + mc] : mc;
  }
  size_t arow[4];
#pragma unroll
  for (int j = 0; j < 4; ++j) {
    const int m = m0 + w * 32 + j * 8 + r8;
    const int mc = m < M ? m : M - 1;
    const int t = tok ? tok[e * T_TOK + mc] : mc;
    arow[j] = (size_t)t * H_DIM + sk;
  }

  auto STAGE = [&](int kt) {
    const int k0 = kt * 64;
#pragma unroll
    for (int j = 0; j < 4; ++j)
      gload16(A + arow[j] + k0, S + (w * 4 + j) * 512);
#pragma unroll
    for (int j = 0; j < 2; ++j) {
      const size_t br = (size_t)(w * 16 + j * 8 + r8) * H_DIM + sk + k0;
      gload16(Bgp + br, S + 8192 + (w * 2 + j) * 512);
      gload16(Bup + br, S + 12288 + (w * 2 + j) * 512);
    }
  };

  const int wr = tid >> 7;
  const int wc = (tid >> 6) & 1;
  const int fr = l & 15;
  const int fg = l >> 4;

  const f32x4 zero = {0.f, 0.f, 0.f, 0.f};
  f32x4 accg[4][2], accu[4][2];
#pragma unroll
  for (int i = 0; i < 4; ++i)
#pragma unroll
    for (int j = 0; j < 2; ++j) { accg[i][j] = zero; accu[i][j] = zero; }

  for (int kt = 0; kt < H_DIM / 64; ++kt) {
    STAGE(kt);
    __syncthreads();
    const u16* AsC = S;
    const u16* BgC = S + 8192;
    const u16* BuC = S + 12288;
#pragma unroll
    for (int kk = 0; kk < 2; ++kk) {
      const int kb = kk * 64 + fg * 16;
      bf16x8 af[4], bg[2], bu[2];
#pragma unroll
      for (int mi = 0; mi < 4; ++mi)
        af[mi] = *(const bf16x8*)lds_sw(AsC, wr * 64 + mi * 16 + fr, kb);
#pragma unroll
      for (int ni = 0; ni < 2; ++ni) {
        bg[ni] = *(const bf16x8*)lds_sw(BgC, wc * 32 + ni * 16 + fr, kb);
        bu[ni] = *(const bf16x8*)lds_sw(BuC, wc * 32 + ni * 16 + fr, kb);
      }
#pragma unroll
      for (int mi = 0; mi < 4; ++mi)
#pragma unroll
        for (int ni = 0; ni < 2; ++ni) {
          accg[mi][ni] = MFMA(af[mi], bg[ni], accg[mi][ni]);
          accu[mi][ni] = MFMA(af[mi], bu[ni], accu[mi][ni]);
        }
    }
    __syncthreads();
  }

  const int colb = n0 + wc * 32;
#pragma unroll
  for (int mi = 0; mi < 4; ++mi) {
#pragma unroll
    for (int r = 0; r < 4; ++r) {
      const int ml = wr * 64 + mi * 16 + fg * 4 + r;
      if (m0 + ml >= M) continue;
      const float wgt = comb ? comb[tokS[ml] * E_NUM + e] : 1.0f;
      const size_t rowoff = (size_t)e * out_e_stride + (size_t)(m0 + ml) * out_stride;
#pragma unroll
      for (int ni = 0; ni < 2; ++ni) {
        float g = accg[mi][ni][r];
        float u = accu[mi][ni][r];
        float sg = g / (1.f + __expf(-g));
        outp[rowoff + colb + ni * 16 + fr] = f2bf(sg * u * wgt);
      }
    }
  }
}

// ---------------- down GEMM core: BM=64, BN=128, single-buffer gload_lds ----------------
template <bool ATOMIC>
__device__ __forceinline__ void down_core(
    const u16* __restrict__ Ap, int astride,
    const u16* __restrict__ Bp, int bstride,
    int NT, int M, int m0, int n0, const int* tokS, float* __restrict__ outp) {
  __shared__ __align__(16) u16 S[12288]; // As 4096, Bs 8192
  const int tid = threadIdx.x;
  const int w = tid >> 6, l = tid & 63;
  const int r8 = l >> 3;
  const int sk = ((l & 7) ^ r8) * 8;

  size_t arow[2];
#pragma unroll
  for (int j = 0; j < 2; ++j) {
    const int m = w * 16 + j * 8 + r8;
    arow[j] = (size_t)(m0 + m < M ? m : (M - 1 - m0 > 0 ? M - 1 - m0 : 0)) * astride + sk;
  }
  size_t brow[4];
#pragma unroll
  for (int j = 0; j < 4; ++j)
    brow[j] = (size_t)(w * 32 + j * 8 + r8) * bstride + sk;

  auto STAGE = [&](int kt) {
    const int k0 = kt * 64;
#pragma unroll
    for (int j = 0; j < 2; ++j)
      gload16(Ap + arow[j] + k0, S + (w * 2 + j) * 512);
#pragma unroll
    for (int j = 0; j < 4; ++j)
      gload16(Bp + brow[j] + k0, S + 4096 + (w * 4 + j) * 512);
  };

  const int fr = l & 15, fg = l >> 4;
  const f32x4 zero = {0.f, 0.f, 0.f, 0.f};
  f32x4 acc[4][2];
#pragma unroll
  for (int i = 0; i < 4; ++i)
#pragma unroll
    for (int j = 0; j < 2; ++j) acc[i][j] = zero;

  for (int kt = 0; kt < NT; ++kt) {
    STAGE(kt);
    __syncthreads();
    const u16* AsC = S;
    const u16* BsC = S + 4096;
#pragma unroll
    for (int kk = 0; kk < 2; ++kk) {
      const int kb = kk * 64 + fg * 16;
      bf16x8 af[4], bfr[2];
#pragma unroll
      for (int mi = 0; mi < 4; ++mi)
        af[mi] = *(const bf16x8*)lds_sw(AsC, mi * 16 + fr, kb);
#pragma unroll
      for (int ni = 0; ni < 2; ++ni)
        bfr[ni] = *(const bf16x8*)lds_sw(BsC, w * 32 + ni * 16 + fr, kb);
#pragma unroll
      for (int mi = 0; mi < 4; ++mi)
#pragma unroll
        for (int ni = 0; ni < 2; ++ni) acc[mi][ni] = MFMA(af[mi], bfr[ni], acc[mi][ni]);
    }
    __syncthreads();
  }

#pragma unroll
  for (int mi = 0; mi < 4; ++mi) {
#pragma unroll
    for (int r = 0; r < 4; ++r) {
      const int ml = mi * 16 + fg * 4 + r;
      if (m0 + ml >= M) continue;
      const int trow = ATOMIC ? tokS[ml] : (m0 + ml);
      float* op = outp + (size_t)trow * H_DIM + n0 + w * 32;
#pragma unroll
      for (int ni = 0; ni < 2; ++ni) {
        if (ATOMIC)
          atomicAdd(op + ni * 16 + fr, acc[mi][ni][r]);
        else
          op[ni * 16 + fr] = acc[mi][ni][r];
      }
    }
  }
}

__global__ __launch_bounds__(256, 4) void down_shared_k(
    const u16* __restrict__ A1, const u16* __restrict__ B1t, float* __restrict__ outp) {
  const int n0 = blockIdx.x * 128, m0 = blockIdx.y * 64;
  down_core<false>(A1 + (size_t)m0 * IS_DIM, IS_DIM, B1t + (size_t)n0 * IS_DIM, IS_DIM,
                   IS_DIM / 64, T_TOK, m0, n0, nullptr, outp);
}

__global__ __launch_bounds__(256, 4) void down_routed_k(
    const u16* __restrict__ ACTC, const u16* __restrict__ WDT,
    const int* __restrict__ cnt, const int* __restrict__ tok, float* __restrict__ outp) {
  const int e = blockIdx.z;
  const int M = cnt[e];
  const int m0 = blockIdx.y * 64;
  if (m0 >= M) return;
  const int n0 = blockIdx.x * 128;
  __shared__ int tokS[64];
  const int tid = threadIdx.x;
  if (tid < 64) tokS[tid] = tok[e * T_TOK + (m0 + tid < M ? m0 + tid : M - 1)];
  __syncthreads();
  down_core<true>(ACTC + ((size_t)e * T_TOK + m0) * I_DIM, I_DIM,
                  WDT + ((size_t)e * H_DIM + n0) * I_DIM, I_DIM,
                  I_DIM / 64, M, m0, n0, tokS, outp);
}

extern "C" void kernel_launch(void* const* d_in, const int* in_sizes, int n_in,
                              void* d_out, int out_size, void* d_ws, size_t ws_size,
                              hipStream_t stream) {
  const float* x    = (const float*)d_in[0];
  const float* wg   = (const float*)d_in[1];
  const float* wgu  = (const float*)d_in[2];
  const float* wd   = (const float*)d_in[3];
  const float* wsgu = (const float*)d_in[4];
  const float* wsd  = (const float*)d_in[5];
  float* out = (float*)d_out;

  char* ws = (char*)d_ws;
  size_t off = 0;
  auto alloc = [&](size_t b) { size_t r = off; off += (b + 255) & ~(size_t)255; return r; };
  u16*   XB    = (u16*)  (ws + alloc((size_t)T_TOK * H_DIM * 2));
  float* COMB  = (float*)(ws + alloc((size_t)T_TOK * E_NUM * 4));
  int*   CNT   = (int*)  (ws + alloc((size_t)E_NUM * 4));
  int*   TOK   = (int*)  (ws + alloc((size_t)E_NUM * T_TOK * 4));
  u16*   WGUT  = (u16*)  (ws + alloc((size_t)E_NUM * 2 * I_DIM * H_DIM * 2)); // [e][1408][2048]
  u16*   WDT   = (u16*)  (ws + alloc((size_t)E_NUM * H_DIM * I_DIM * 2));     // [e][2048][704]
  u16*   WSGUT = (u16*)  (ws + alloc((size_t)2 * IS_DIM * H_DIM * 2));        // [2816][2048]
  u16*   WSDT  = (u16*)  (ws + alloc((size_t)H_DIM * IS_DIM * 2));            // [2048][1408]
  u16*   ACTC  = (u16*)  (ws + alloc((size_t)E_NUM * T_TOK * I_DIM * 2));     // [e][1024][704]
  u16*   ACTS  = (u16*)  (ws + alloc((size_t)T_TOK * IS_DIM * 2));            // [1024][1408]
  if (ws_size < off) return;

  conv_x_k<<<(T_TOK * H_DIM) / (256 * 8), 256, 0, stream>>>(x, XB);
  router_k<<<T_TOK, 256, 0, stream>>>(x, wg, COMB);
  dispatch_k<<<E_NUM, 256, 0, stream>>>(COMB, CNT, TOK);
  // weight transposes fp32 -> bf16 [N][K]
  transp_k<128><<<dim3(22, 16, 16), 256, 0, stream>>>(wgu, WGUT, H_DIM, 2 * I_DIM);
  transp_k<64><<<dim3(32, 11, 16), 256, 0, stream>>>(wd, WDT, I_DIM, H_DIM);
  transp_k<128><<<dim3(44, 16, 1), 256, 0, stream>>>(wsgu, WSGUT, H_DIM, 2 * IS_DIM);
  transp_k<128><<<dim3(32, 11, 1), 256, 0, stream>>>(wsd, WSDT, IS_DIM, H_DIM);
  // routed gate/up on dispatched tokens -> compact act [e][row][704]
  gu_act_k<<<dim3(I_DIM / 64, T_TOK / 128, E_NUM), 256, 0, stream>>>(
      XB, WGUT, COMB, CNT, TOK, ACTC, I_DIM, (long long)(2 * I_DIM) * H_DIM,
      (long long)T_TOK * I_DIM, I_DIM);
  // shared gate/up (dense)
  gu_act_k<<<dim3(IS_DIM / 64, T_TOK / 128, 1), 256, 0, stream>>>(
      XB, WSGUT, nullptr, nullptr, nullptr, ACTS, IS_DIM, 0, 0, IS_DIM);
  // shared down writes out, then routed down accumulates atomically
  down_shared_k<<<dim3(H_DIM / 128, T_TOK / 64), 256, 0, stream>>>(ACTS, WSDT, out);
  down_routed_k<<<dim3(H_DIM / 128, T_TOK / 64, E_NUM), 256, 0, stream>>>(
      ACTC, WDT, CNT, TOK, out);
}